// Round 3
// baseline (813.472 us; speedup 1.0000x reference)
//
#include <hip/hip_runtime.h>
#include <math.h>

constexpr int B = 4, C = 64, H = 96, W = 96, HW = H * W;

// ---- workspace layout (float offsets) ----
constexpr size_t OFF_OFFALL = 0;                              // B*72*HW
constexpr size_t OFF_X1     = OFF_OFFALL + (size_t)B*72*HW;   // raw deform1 sum (no bias/lrelu)
constexpr size_t OFF_X2     = OFF_X1 + (size_t)B*64*HW;       // raw deform3 sum
constexpr size_t OFF_X3A    = OFF_X2 + (size_t)B*64*HW;       // raw deform5 partial n[0,13)
constexpr size_t OFF_X3B    = OFF_X3A + (size_t)B*64*HW;      // raw deform5 partial n[13,25)
constexpr size_t OFF_WOT    = OFF_X3B + (size_t)B*64*HW;      // 64*9*72 [ic][tap][oc]
constexpr size_t OFF_BOALL  = OFF_WOT + (size_t)64*9*72;      // 72
constexpr size_t OFF_W1T    = OFF_BOALL + 72;                 // [n][c][o]
constexpr size_t OFF_W3T    = OFF_W1T + (size_t)64*64;
constexpr size_t OFF_W5T    = OFF_W3T + (size_t)9*64*64;
constexpr size_t OFF_WEFF   = OFF_W5T + (size_t)25*64*64;     // 64*25*64 [ic][tap][oc]
constexpr size_t OFF_BEFF   = OFF_WEFF + (size_t)64*25*64;    // 64

// ---------------- single prep kernel ----------------
__global__ void prep_all(const float* __restrict__ wo1, const float* __restrict__ bo1,
                         const float* __restrict__ wo3, const float* __restrict__ bo3,
                         const float* __restrict__ wo5, const float* __restrict__ bo5,
                         const float* __restrict__ w1, const float* __restrict__ w3,
                         const float* __restrict__ w5,
                         const float* __restrict__ wa1, const float* __restrict__ ba1,
                         const float* __restrict__ wa3, const float* __restrict__ ba3,
                         const float* __restrict__ wa5, const float* __restrict__ ba5,
                         float* __restrict__ woT, float* __restrict__ boAll,
                         float* __restrict__ w1T, float* __restrict__ w3T,
                         float* __restrict__ w5T,
                         float* __restrict__ weff, float* __restrict__ beff) {
  int idx = blockIdx.x * 256 + threadIdx.x;
  if (idx < 41472) {  // woT [ic64][tap9][oc72]
    int ic = idx / (9 * 72), tap = (idx / 72) % 9, oc = idx % 72;
    float v = 0.f;
    if (oc < 2)       v = wo1[(oc * 64 + ic) * 9 + tap];
    else if (oc < 20) v = wo3[((oc - 2) * 64 + ic) * 9 + tap];
    else if (oc < 70) v = wo5[((oc - 20) * 64 + ic) * 9 + tap];
    woT[idx] = v;
  }
  if (idx < 72) boAll[idx] = idx < 2 ? bo1[idx] : idx < 20 ? bo3[idx - 2] : idx < 70 ? bo5[idx - 20] : 0.f;
  if (idx < 64) beff[idx] = ba1[idx] + ba3[idx] + ba5[idx];
  int i2 = idx - 41472;  // wT ranges, 35*4096
  if (i2 >= 0 && i2 < 143360) {
    int seg = i2 >> 12, rem = i2 & 4095;
    int c = rem >> 6, o = rem & 63;
    if (seg < 1)       w1T[rem]                     = w1[o * 64 + c];
    else if (seg < 10) w3T[(seg - 1) * 4096 + rem]  = w3[(o * 64 + c) * 9 + (seg - 1)];
    else               w5T[(seg - 10) * 4096 + rem] = w5[(o * 64 + c) * 25 + (seg - 10)];
  }
  int i3 = idx - 41472 - 143360;  // weff 64*25*64
  if (i3 >= 0 && i3 < 102400) {
    int ic = i3 / 1600, tap = (i3 / 64) % 25, oc = i3 & 63;
    int kh = tap / 5, kw = tap % 5;
    float v = wa5[(oc * 64 + ic) * 25 + tap];
    if (kh >= 1 && kh <= 3 && kw >= 1 && kw <= 3)
      v += wa3[(oc * 64 + ic) * 9 + (kh - 1) * 3 + (kw - 1)];
    if (tap == 12) v += wa1[oc * 64 + ic];
    weff[i3] = v;
  }
}

// ---------------- offset conv: 3x3 pad1, 64->72 channels ----------------
__global__ __launch_bounds__(256) void conv_off(const float* __restrict__ x,
                                                const float* __restrict__ woT,
                                                const float* __restrict__ boAll,
                                                float* __restrict__ offAll) {
  __shared__ __align__(16) float xs[16][3][100];
  __shared__ __align__(16) float wsh[16 * 9 * 72];
  const int h = blockIdx.x, b = blockIdx.y;
  const int tid = threadIdx.x;
  const int ocg = tid >> 5, pixg = tid & 31;
  const int oc0 = ocg * 9, w0 = pixg * 3;
  float acc[9][3] = {};

  for (int cc = 0; cc < 4; ++cc) {
    __syncthreads();
    for (int idx = tid; idx < 4800; idx += 256) {
      int ic = idx / 300;
      int r  = (idx / 100) % 3;
      int j  = idx % 100;
      int wc = j - 1, hr = h - 1 + r;
      float v = 0.f;
      if (wc >= 0 && wc < 96 && hr >= 0 && hr < 96)
        v = x[((size_t)(b * 64 + cc * 16 + ic) * 96 + hr) * 96 + wc];
      xs[ic][r][j] = v;
    }
    {
      const float4* src = reinterpret_cast<const float4*>(woT + cc * 10368);
      float4* dst = reinterpret_cast<float4*>(wsh);
      for (int i = tid; i < 10368 / 4; i += 256) dst[i] = src[i];
    }
    __syncthreads();
#pragma unroll 2
    for (int ic = 0; ic < 16; ++ic) {
#pragma unroll
      for (int kh = 0; kh < 3; ++kh) {
        float xv[5];
#pragma unroll
        for (int t = 0; t < 5; ++t) xv[t] = xs[ic][kh][w0 + t];
#pragma unroll
        for (int kw = 0; kw < 3; ++kw) {
          const float* wrow = &wsh[(ic * 9 + kh * 3 + kw) * 72 + oc0];
#pragma unroll
          for (int o = 0; o < 9; ++o) {
            float wv = wrow[o];
            acc[o][0] += wv * xv[kw + 0];
            acc[o][1] += wv * xv[kw + 1];
            acc[o][2] += wv * xv[kw + 2];
          }
        }
      }
    }
  }
#pragma unroll
  for (int o = 0; o < 9; ++o) {
    int oc = oc0 + o;
    float bias = boAll[oc];
#pragma unroll
    for (int p = 0; p < 3; ++p)
      offAll[((size_t)(b * 72 + oc) * 96 + h) * 96 + w0 + p] = acc[o][p] + bias;
  }
}

// ---------------- deformable conv body: 2 rows, raw partial sums ----------------
template <int KS>
__device__ __forceinline__ void deform_body(const float* __restrict__ x,
                                            const float* __restrict__ offAll,
                                            const float* __restrict__ wT,
                                            float* __restrict__ dst,
                                            int n0, int n1,
                                            float* __restrict__ xoffn,   // [32*192]
                                            float* __restrict__ wn,      // [32*64]
                                            int* __restrict__ sp_i,      // [4*192]
                                            float* __restrict__ sp_g,    // [4*192]
                                            int h0, int b, int tid) {
  constexpr int N = KS * KS, P = (KS - 1) / 2, HP = H + 2 * P;
  constexpr int CHB = (KS == 1) ? 0 : (KS == 3) ? 2 : 20;
  const int ocg = tid >> 6, lane = tid & 63, row = lane >> 5, colg = lane & 31;
  const int oc0 = ocg * 16, w0 = colg * 3;
  float acc[16][3] = {};
  const float* xb = x + (size_t)b * 64 * HW;

  for (int n = n0; n < n1; ++n) {
    if (tid < 192) {
      int w = tid % 96, r = tid / 96, h = h0 + r;
      float ox = offAll[((size_t)(b * 72 + CHB + n) * 96 + h) * 96 + w];
      float oy = offAll[((size_t)(b * 72 + CHB + N + n) * 96 + h) * 96 + w];
      float px = ox + (float)(h + 1 + n / KS - P);
      float py = oy + (float)(w + 1 + n % KS - P);
      float fx = floorf(px), fy = floorf(py);
      float hpm = (float)(HP - 1);
      float ltx = fminf(fmaxf(fx, 0.f), hpm);
      float rbx = fminf(fmaxf(fx + 1.f, 0.f), hpm);
      float lty = fminf(fmaxf(fy, 0.f), hpm);
      float rby = fminf(fmaxf(fy + 1.f, 0.f), hpm);
      float pxc = fminf(fmaxf(px, 0.f), hpm);
      float pyc = fminf(fmaxf(py, 0.f), hpm);
      float gx0 = 1.f + (ltx - pxc);
      float gx1 = 1.f - (rbx - pxc);
      float gy0 = 1.f + (lty - pyc);
      float gy1 = 1.f - (rby - pyc);
      sp_i[0 * 192 + tid] = (int)ltx; sp_i[1 * 192 + tid] = (int)rbx;
      sp_i[2 * 192 + tid] = (int)lty; sp_i[3 * 192 + tid] = (int)rby;
      sp_g[0 * 192 + tid] = gx0 * gy0;  // (ltx,lty)
      sp_g[1 * 192 + tid] = gx1 * gy1;  // (rbx,rby)
      sp_g[2 * 192 + tid] = gx0 * gy1;  // (ltx,rby)
      sp_g[3 * 192 + tid] = gx1 * gy0;  // (rbx,lty)
    }
    __syncthreads();
    for (int cc = 0; cc < 2; ++cc) {
      {  // stage 32x64 weight chunk
        const float4* src = reinterpret_cast<const float4*>(wT + (size_t)n * 4096 + cc * 2048);
        float4* dw = reinterpret_cast<float4*>(wn);
        dw[tid] = src[tid];
        dw[tid + 256] = src[tid + 256];
      }
#pragma unroll 2
      for (int it = 0; it < 24; ++it) {  // gather 32ch x 192px
        int idx = it * 256 + tid;
        int cl = idx / 192, rp = idx % 192;
        int ix0 = sp_i[0 * 192 + rp], ix1 = sp_i[1 * 192 + rp];
        int iy0 = sp_i[2 * 192 + rp], iy1 = sp_i[3 * 192 + rp];
        const float* xc = xb + (size_t)(cc * 32 + cl) * HW;
        float v00, v11, v01, v10;
        if constexpr (P == 0) {
          v00 = xc[ix0 * 96 + iy0];
          v11 = xc[ix1 * 96 + iy1];
          v01 = xc[ix0 * 96 + iy1];
          v10 = xc[ix1 * 96 + iy0];
        } else {
          int rx0 = ix0 - P, rx1 = ix1 - P, ry0 = iy0 - P, ry1 = iy1 - P;
          bool bx0 = (rx0 >= 0) && (rx0 < 96), bx1 = (rx1 >= 0) && (rx1 < 96);
          bool by0 = (ry0 >= 0) && (ry0 < 96), by1 = (ry1 >= 0) && (ry1 < 96);
          v00 = (bx0 && by0) ? xc[rx0 * 96 + ry0] : 0.f;
          v11 = (bx1 && by1) ? xc[rx1 * 96 + ry1] : 0.f;
          v01 = (bx0 && by1) ? xc[rx0 * 96 + ry1] : 0.f;
          v10 = (bx1 && by0) ? xc[rx1 * 96 + ry0] : 0.f;
        }
        xoffn[idx] = sp_g[0 * 192 + rp] * v00 + sp_g[1 * 192 + rp] * v11 +
                     sp_g[2 * 192 + rp] * v01 + sp_g[3 * 192 + rp] * v10;
      }
      __syncthreads();
#pragma unroll 2
      for (int cl = 0; cl < 32; ++cl) {  // contract 16oc x 3px
        float xv0 = xoffn[cl * 192 + row * 96 + w0];
        float xv1 = xoffn[cl * 192 + row * 96 + w0 + 1];
        float xv2 = xoffn[cl * 192 + row * 96 + w0 + 2];
        const float4* wp = reinterpret_cast<const float4*>(wn + cl * 64 + oc0);
        float4 wa = wp[0], wb = wp[1], wc = wp[2], wd = wp[3];
        float wv[16] = {wa.x, wa.y, wa.z, wa.w, wb.x, wb.y, wb.z, wb.w,
                        wc.x, wc.y, wc.z, wc.w, wd.x, wd.y, wd.z, wd.w};
#pragma unroll
        for (int o = 0; o < 16; ++o) {
          acc[o][0] += wv[o] * xv0;
          acc[o][1] += wv[o] * xv1;
          acc[o][2] += wv[o] * xv2;
        }
      }
      __syncthreads();
    }
  }
#pragma unroll
  for (int o = 0; o < 16; ++o) {
    int oc = oc0 + o;
    size_t base = ((size_t)(b * 64 + oc) * 96 + (h0 + row)) * 96 + w0;
    dst[base + 0] = acc[o][0];
    dst[base + 1] = acc[o][1];
    dst[base + 2] = acc[o][2];
  }
}

// 768 blocks; mapping makes per-CU work sums ~{26,27} under round-robin dispatch
__global__ __launch_bounds__(256, 4) void deform_all(const float* __restrict__ x,
                                                     const float* __restrict__ offAll,
                                                     const float* __restrict__ w1T,
                                                     const float* __restrict__ w3T,
                                                     const float* __restrict__ w5T,
                                                     float* __restrict__ x1,
                                                     float* __restrict__ x2,
                                                     float* __restrict__ x3a,
                                                     float* __restrict__ x3b) {
  __shared__ __align__(16) float xoffn[32 * 192];
  __shared__ __align__(16) float wn[32 * 64];
  __shared__ int   sp_i[4 * 192];
  __shared__ float sp_g[4 * 192];
  int bid = blockIdx.x;
  int typ, idx;
  if (bid < 192)      { typ = 0; idx = bid; }           // KS5 n[0,13)  13u
  else if (bid < 256) { typ = 3; idx = bid - 192; }     // KS3 (part1)   9u
  else if (bid < 448) { typ = 1; idx = bid - 256; }     // KS5 n[13,25) 12u
  else if (bid < 512) { typ = 3; idx = 64 + (bid - 448); }
  else if (bid < 704) { typ = 2; idx = bid - 512; }     // KS1           1u
  else                { typ = 3; idx = 128 + (bid - 704); }
  int h0 = (idx % 48) * 2, b = idx / 48;
  int tid = threadIdx.x;
  if (typ == 0)      deform_body<5>(x, offAll, w5T, x3a, 0, 13, xoffn, wn, sp_i, sp_g, h0, b, tid);
  else if (typ == 1) deform_body<5>(x, offAll, w5T, x3b, 13, 25, xoffn, wn, sp_i, sp_g, h0, b, tid);
  else if (typ == 2) deform_body<1>(x, offAll, w1T, x1, 0, 1, xoffn, wn, sp_i, sp_g, h0, b, tid);
  else               deform_body<3>(x, offAll, w3T, x2, 0, 9, xoffn, wn, sp_i, sp_g, h0, b, tid);
}

// ---------------- attention (combined 5x5) + final; 768 blocks = 3/CU ----------------
__global__ __launch_bounds__(128, 2) void att_final(const float* __restrict__ x1,
                                                    const float* __restrict__ x2,
                                                    const float* __restrict__ x3a,
                                                    const float* __restrict__ x3b,
                                                    const float* __restrict__ b1,
                                                    const float* __restrict__ b3,
                                                    const float* __restrict__ b5,
                                                    const float* __restrict__ weff,
                                                    const float* __restrict__ beff,
                                                    float* __restrict__ out) {
  __shared__ __align__(16) float xs[4 * 5 * 100];
  __shared__ __align__(16) float wsh[4 * 25 * 32];
  __shared__ float bsh[3][64];
  const int h = blockIdx.x, b = blockIdx.y, zoc = blockIdx.z * 32;
  const int tid = threadIdx.x;
  const int ocg = tid >> 5, colg = tid & 31;
  const int oc0 = ocg * 8, w0 = colg * 3;
  if (tid < 64) { bsh[0][tid] = b1[tid]; bsh[1][tid] = b3[tid]; bsh[2][tid] = b5[tid]; }
  float acc[8][3] = {};

  for (int cc = 0; cc < 16; ++cc) {
    __syncthreads();
    for (int idx = tid; idx < 2000; idx += 128) {
      int ic = idx / 500, r = (idx / 100) % 5, j = idx % 100;
      int hr = h - 2 + r, wc = j - 2;
      float v = 0.f;
      int c = cc * 4 + ic;
      if (hr >= 0 && hr < 96 && wc >= 0 && wc < 96) {
        size_t ii = ((size_t)(b * 64 + c) * 96 + hr) * 96 + wc;
        float a1 = x1[ii] + bsh[0][c]; a1 = a1 >= 0.f ? a1 : 0.1f * a1;
        float a2 = x2[ii] + bsh[1][c]; a2 = a2 >= 0.f ? a2 : 0.1f * a2;
        float a3 = x3a[ii] + x3b[ii] + bsh[2][c]; a3 = a3 >= 0.f ? a3 : 0.1f * a3;
        v = a1 + a2 + a3;
      }
      xs[idx] = v;
    }
    for (int i = tid; i < 800; i += 128) {  // wsh[ic][tap][32]
      int ict = i >> 3, o4 = i & 7;
      int ic = ict / 25, tap = ict % 25;
      reinterpret_cast<float4*>(wsh)[i] =
          *reinterpret_cast<const float4*>(weff + ((size_t)(cc * 4 + ic) * 25 + tap) * 64 + zoc + o4 * 4);
    }
    __syncthreads();
#pragma unroll
    for (int ic = 0; ic < 4; ++ic) {
#pragma unroll
      for (int kh = 0; kh < 5; ++kh) {
        float xv[7];
#pragma unroll
        for (int t = 0; t < 7; ++t) xv[t] = xs[ic * 500 + kh * 100 + w0 + t];
#pragma unroll
        for (int kw = 0; kw < 5; ++kw) {
          const float4* wp = reinterpret_cast<const float4*>(&wsh[(ic * 25 + kh * 5 + kw) * 32 + oc0]);
          float4 wa = wp[0], wb = wp[1];
          float wv[8] = {wa.x, wa.y, wa.z, wa.w, wb.x, wb.y, wb.z, wb.w};
#pragma unroll
          for (int o = 0; o < 8; ++o) {
            acc[o][0] += wv[o] * xv[kw + 0];
            acc[o][1] += wv[o] * xv[kw + 1];
            acc[o][2] += wv[o] * xv[kw + 2];
          }
        }
      }
    }
  }
#pragma unroll
  for (int o = 0; o < 8; ++o) {
    int oc = zoc + oc0 + o;
    float bz = beff[oc];
#pragma unroll
    for (int p = 0; p < 3; ++p) {
      float z = acc[o][p] + bz;
      float att = 1.f / (1.f + __expf(-z));
      size_t oi = ((size_t)(b * 64 + oc) * 96 + h) * 96 + w0 + p;
      float a1 = x1[oi] + bsh[0][oc]; a1 = a1 >= 0.f ? a1 : 0.1f * a1;
      float a2 = x2[oi] + bsh[1][oc]; a2 = a2 >= 0.f ? a2 : 0.1f * a2;
      float a3 = x3a[oi] + x3b[oi] + bsh[2][oc]; a3 = a3 >= 0.f ? a3 : 0.1f * a3;
      float m = a1 + a2 + a3;
      out[oi] = m + m * att;
    }
  }
}

// ---------------- launch ----------------
extern "C" void kernel_launch(void* const* d_in, const int* in_sizes, int n_in,
                              void* d_out, int out_size, void* d_ws, size_t ws_size,
                              hipStream_t stream) {
  const float* x   = (const float*)d_in[0];
  const float* wo1 = (const float*)d_in[1];
  const float* bo1 = (const float*)d_in[2];
  const float* w1  = (const float*)d_in[3];
  const float* b1  = (const float*)d_in[4];
  const float* wa1 = (const float*)d_in[5];
  const float* ba1 = (const float*)d_in[6];
  const float* wo3 = (const float*)d_in[7];
  const float* bo3 = (const float*)d_in[8];
  const float* w3  = (const float*)d_in[9];
  const float* b3  = (const float*)d_in[10];
  const float* wa3 = (const float*)d_in[11];
  const float* ba3 = (const float*)d_in[12];
  const float* wo5 = (const float*)d_in[13];
  const float* bo5 = (const float*)d_in[14];
  const float* w5  = (const float*)d_in[15];
  const float* b5  = (const float*)d_in[16];
  const float* wa5 = (const float*)d_in[17];
  const float* ba5 = (const float*)d_in[18];

  float* ws     = (float*)d_ws;
  float* offAll = ws + OFF_OFFALL;
  float* x1     = ws + OFF_X1;
  float* x2     = ws + OFF_X2;
  float* x3a    = ws + OFF_X3A;
  float* x3b    = ws + OFF_X3B;
  float* woT    = ws + OFF_WOT;
  float* boAll  = ws + OFF_BOALL;
  float* w1T    = ws + OFF_W1T;
  float* w3T    = ws + OFF_W3T;
  float* w5T    = ws + OFF_W5T;
  float* weff   = ws + OFF_WEFF;
  float* beff   = ws + OFF_BEFF;

  float* out = (float*)d_out;

  hipLaunchKernelGGL(prep_all, dim3(1122), dim3(256), 0, stream,
                     wo1, bo1, wo3, bo3, wo5, bo5, w1, w3, w5,
                     wa1, ba1, wa3, ba3, wa5, ba5,
                     woT, boAll, w1T, w3T, w5T, weff, beff);
  hipLaunchKernelGGL(conv_off, dim3(96, 4), dim3(256), 0, stream, x, woT, boAll, offAll);
  hipLaunchKernelGGL(deform_all, dim3(768), dim3(256), 0, stream,
                     x, offAll, w1T, w3T, w5T, x1, x2, x3a, x3b);
  hipLaunchKernelGGL(att_final, dim3(96, 4, 2), dim3(128), 0, stream,
                     x1, x2, x3a, x3b, b1, b3, b5, weff, beff, out);
}

// Round 4
// 750.151 us; speedup vs baseline: 1.0844x; 1.0844x over previous
//
#include <hip/hip_runtime.h>
#include <math.h>

constexpr int B = 4, C = 64, H = 96, W = 96, HW = H * W;

// ---- workspace layout (float offsets) ----
constexpr size_t OFF_OFFALL = 0;                              // B*72*HW offsets (dead after deform_all)
constexpr size_t OFF_MSF    = OFF_OFFALL;                     // alias: msf written after offAll's last read
constexpr size_t OFF_X1     = OFF_OFFALL + (size_t)B*72*HW;   // raw deform1 sum
constexpr size_t OFF_X2     = OFF_X1  + (size_t)B*64*HW;      // raw deform3 sum
constexpr size_t OFF_X3A    = OFF_X2  + (size_t)B*64*HW;      // raw deform5 n[0,9)
constexpr size_t OFF_X3B    = OFF_X3A + (size_t)B*64*HW;      // raw deform5 n[9,17)
constexpr size_t OFF_X3C    = OFF_X3B + (size_t)B*64*HW;      // raw deform5 n[17,25)
constexpr size_t OFF_WOT    = OFF_X3C + (size_t)B*64*HW;      // 64*9*72 [ic][tap][oc]
constexpr size_t OFF_BOALL  = OFF_WOT + (size_t)64*9*72;      // 72
constexpr size_t OFF_W1T    = OFF_BOALL + 72;                 // [n][c][o]
constexpr size_t OFF_W3T    = OFF_W1T + (size_t)64*64;
constexpr size_t OFF_W5T    = OFF_W3T + (size_t)9*64*64;
constexpr size_t OFF_WEFF   = OFF_W5T + (size_t)25*64*64;     // 64*25*64 [ic][tap][oc]
constexpr size_t OFF_BEFF   = OFF_WEFF + (size_t)64*25*64;    // 64

// ---------------- single prep kernel ----------------
__global__ void prep_all(const float* __restrict__ wo1, const float* __restrict__ bo1,
                         const float* __restrict__ wo3, const float* __restrict__ bo3,
                         const float* __restrict__ wo5, const float* __restrict__ bo5,
                         const float* __restrict__ w1, const float* __restrict__ w3,
                         const float* __restrict__ w5,
                         const float* __restrict__ wa1, const float* __restrict__ ba1,
                         const float* __restrict__ wa3, const float* __restrict__ ba3,
                         const float* __restrict__ wa5, const float* __restrict__ ba5,
                         float* __restrict__ woT, float* __restrict__ boAll,
                         float* __restrict__ w1T, float* __restrict__ w3T,
                         float* __restrict__ w5T,
                         float* __restrict__ weff, float* __restrict__ beff) {
  int idx = blockIdx.x * 256 + threadIdx.x;
  if (idx < 41472) {  // woT [ic64][tap9][oc72]
    int ic = idx / (9 * 72), tap = (idx / 72) % 9, oc = idx % 72;
    float v = 0.f;
    if (oc < 2)       v = wo1[(oc * 64 + ic) * 9 + tap];
    else if (oc < 20) v = wo3[((oc - 2) * 64 + ic) * 9 + tap];
    else if (oc < 70) v = wo5[((oc - 20) * 64 + ic) * 9 + tap];
    woT[idx] = v;
  }
  if (idx < 72) boAll[idx] = idx < 2 ? bo1[idx] : idx < 20 ? bo3[idx - 2] : idx < 70 ? bo5[idx - 20] : 0.f;
  if (idx < 64) beff[idx] = ba1[idx] + ba3[idx] + ba5[idx];
  int i2 = idx - 41472;  // wT ranges, 35*4096
  if (i2 >= 0 && i2 < 143360) {
    int seg = i2 >> 12, rem = i2 & 4095;
    int c = rem >> 6, o = rem & 63;
    if (seg < 1)       w1T[rem]                     = w1[o * 64 + c];
    else if (seg < 10) w3T[(seg - 1) * 4096 + rem]  = w3[(o * 64 + c) * 9 + (seg - 1)];
    else               w5T[(seg - 10) * 4096 + rem] = w5[(o * 64 + c) * 25 + (seg - 10)];
  }
  int i3 = idx - 41472 - 143360;  // weff 64*25*64
  if (i3 >= 0 && i3 < 102400) {
    int ic = i3 / 1600, tap = (i3 / 64) % 25, oc = i3 & 63;
    int kh = tap / 5, kw = tap % 5;
    float v = wa5[(oc * 64 + ic) * 25 + tap];
    if (kh >= 1 && kh <= 3 && kw >= 1 && kw <= 3)
      v += wa3[(oc * 64 + ic) * 9 + (kh - 1) * 3 + (kw - 1)];
    if (tap == 12) v += wa1[oc * 64 + ic];
    weff[i3] = v;
  }
}

// ---------------- offset conv: 3x3 pad1, 64->72 ch; ic chunked by 8 (LDS 30KB, 5 blk/CU) ----------------
__global__ __launch_bounds__(256) void conv_off(const float* __restrict__ x,
                                                const float* __restrict__ woT,
                                                const float* __restrict__ boAll,
                                                float* __restrict__ offAll) {
  __shared__ __align__(16) float xs[8][3][100];
  __shared__ __align__(16) float wsh[8 * 9 * 72];
  const int h = blockIdx.x, b = blockIdx.y;
  const int tid = threadIdx.x;
  const int ocg = tid >> 5, pixg = tid & 31;
  const int oc0 = ocg * 9, w0 = pixg * 3;
  float acc[9][3] = {};

  for (int cc = 0; cc < 8; ++cc) {
    __syncthreads();
    for (int idx = tid; idx < 2400; idx += 256) {
      int ic = idx / 300;
      int r  = (idx / 100) % 3;
      int j  = idx % 100;
      int wc = j - 1, hr = h - 1 + r;
      float v = 0.f;
      if (wc >= 0 && wc < 96 && hr >= 0 && hr < 96)
        v = x[((size_t)(b * 64 + cc * 8 + ic) * 96 + hr) * 96 + wc];
      xs[ic][r][j] = v;
    }
    {
      const float4* src = reinterpret_cast<const float4*>(woT + cc * 5184);
      float4* dst = reinterpret_cast<float4*>(wsh);
      for (int i = tid; i < 1296; i += 256) dst[i] = src[i];
    }
    __syncthreads();
#pragma unroll 2
    for (int ic = 0; ic < 8; ++ic) {
#pragma unroll
      for (int kh = 0; kh < 3; ++kh) {
        float xv[5];
#pragma unroll
        for (int t = 0; t < 5; ++t) xv[t] = xs[ic][kh][w0 + t];
#pragma unroll
        for (int kw = 0; kw < 3; ++kw) {
          const float* wrow = &wsh[(ic * 9 + kh * 3 + kw) * 72 + oc0];
#pragma unroll
          for (int o = 0; o < 9; ++o) {
            float wv = wrow[o];
            acc[o][0] += wv * xv[kw + 0];
            acc[o][1] += wv * xv[kw + 1];
            acc[o][2] += wv * xv[kw + 2];
          }
        }
      }
    }
  }
#pragma unroll
  for (int o = 0; o < 9; ++o) {
    int oc = oc0 + o;
    float bias = boAll[oc];
#pragma unroll
    for (int p = 0; p < 3; ++p)
      offAll[((size_t)(b * 72 + oc) * 96 + h) * 96 + w0 + p] = acc[o][p] + bias;
  }
}

// ---------------- deformable conv body: 1 row, 64 oc, raw partial sums ----------------
template <int KS>
__device__ __forceinline__ void deform_body(const float* __restrict__ x,
                                            const float* __restrict__ offAll,
                                            const float* __restrict__ wT,
                                            float* __restrict__ dst,
                                            int n0, int n1,
                                            float* __restrict__ xoffn,   // [32*96]
                                            float* __restrict__ wn,      // [32*64]
                                            int* __restrict__ sp_i,      // [4*96]
                                            float* __restrict__ sp_g,    // [4*96]
                                            int h, int b, int tid) {
  constexpr int N = KS * KS, P = (KS - 1) / 2, HP = H + 2 * P;
  constexpr int CHB = (KS == 1) ? 0 : (KS == 3) ? 2 : 20;
  const int ocg = tid >> 5, pixg = tid & 31;
  const int oc0 = ocg * 8, w0 = pixg * 3;
  float acc[8][3] = {};
  const float* xb = x + (size_t)b * 64 * HW;

  for (int n = n0; n < n1; ++n) {
    if (tid < 96) {
      int w = tid;
      float ox = offAll[((size_t)(b * 72 + CHB + n) * 96 + h) * 96 + w];
      float oy = offAll[((size_t)(b * 72 + CHB + N + n) * 96 + h) * 96 + w];
      float px = ox + (float)(h + 1 + n / KS - P);
      float py = oy + (float)(w + 1 + n % KS - P);
      float fx = floorf(px), fy = floorf(py);
      float hpm = (float)(HP - 1);
      float ltx = fminf(fmaxf(fx, 0.f), hpm);
      float rbx = fminf(fmaxf(fx + 1.f, 0.f), hpm);
      float lty = fminf(fmaxf(fy, 0.f), hpm);
      float rby = fminf(fmaxf(fy + 1.f, 0.f), hpm);
      float pxc = fminf(fmaxf(px, 0.f), hpm);
      float pyc = fminf(fmaxf(py, 0.f), hpm);
      float gx0 = 1.f + (ltx - pxc);
      float gx1 = 1.f - (rbx - pxc);
      float gy0 = 1.f + (lty - pyc);
      float gy1 = 1.f - (rby - pyc);
      sp_i[0 * 96 + w] = (int)ltx; sp_i[1 * 96 + w] = (int)rbx;
      sp_i[2 * 96 + w] = (int)lty; sp_i[3 * 96 + w] = (int)rby;
      sp_g[0 * 96 + w] = gx0 * gy0;  // (ltx,lty)
      sp_g[1 * 96 + w] = gx1 * gy1;  // (rbx,rby)
      sp_g[2 * 96 + w] = gx0 * gy1;  // (ltx,rby)
      sp_g[3 * 96 + w] = gx1 * gy0;  // (rbx,lty)
    }
    __syncthreads();
    for (int cc = 0; cc < 2; ++cc) {
      {  // stage 32x64 weight chunk
        const float4* src = reinterpret_cast<const float4*>(wT + (size_t)n * 4096 + cc * 2048);
        float4* dw = reinterpret_cast<float4*>(wn);
        dw[tid] = src[tid];
        dw[tid + 256] = src[tid + 256];
      }
#pragma unroll 4
      for (int it = 0; it < 12; ++it) {  // gather 32ch x 96px
        int idx = it * 256 + tid;
        int cl = idx / 96, rp = idx - cl * 96;
        int ix0 = sp_i[0 * 96 + rp], ix1 = sp_i[1 * 96 + rp];
        int iy0 = sp_i[2 * 96 + rp], iy1 = sp_i[3 * 96 + rp];
        const float* xc = xb + (size_t)(cc * 32 + cl) * HW;
        float v00, v11, v01, v10;
        if constexpr (P == 0) {
          v00 = xc[ix0 * 96 + iy0];
          v11 = xc[ix1 * 96 + iy1];
          v01 = xc[ix0 * 96 + iy1];
          v10 = xc[ix1 * 96 + iy0];
        } else {
          int rx0 = ix0 - P, rx1 = ix1 - P, ry0 = iy0 - P, ry1 = iy1 - P;
          bool bx0 = (rx0 >= 0) && (rx0 < 96), bx1 = (rx1 >= 0) && (rx1 < 96);
          bool by0 = (ry0 >= 0) && (ry0 < 96), by1 = (ry1 >= 0) && (ry1 < 96);
          v00 = (bx0 && by0) ? xc[rx0 * 96 + ry0] : 0.f;
          v11 = (bx1 && by1) ? xc[rx1 * 96 + ry1] : 0.f;
          v01 = (bx0 && by1) ? xc[rx0 * 96 + ry1] : 0.f;
          v10 = (bx1 && by0) ? xc[rx1 * 96 + ry0] : 0.f;
        }
        xoffn[idx] = sp_g[0 * 96 + rp] * v00 + sp_g[1 * 96 + rp] * v11 +
                     sp_g[2 * 96 + rp] * v01 + sp_g[3 * 96 + rp] * v10;
      }
      __syncthreads();
#pragma unroll 2
      for (int cl = 0; cl < 32; ++cl) {  // contract 8oc x 3px
        float xv0 = xoffn[cl * 96 + w0];
        float xv1 = xoffn[cl * 96 + w0 + 1];
        float xv2 = xoffn[cl * 96 + w0 + 2];
        const float4* wp = reinterpret_cast<const float4*>(wn + cl * 64 + oc0);
        float4 wa = wp[0], wb = wp[1];
        float wv[8] = {wa.x, wa.y, wa.z, wa.w, wb.x, wb.y, wb.z, wb.w};
#pragma unroll
        for (int o = 0; o < 8; ++o) {
          acc[o][0] += wv[o] * xv0;
          acc[o][1] += wv[o] * xv1;
          acc[o][2] += wv[o] * xv2;
        }
      }
      __syncthreads();
    }
  }
#pragma unroll
  for (int o = 0; o < 8; ++o) {
    int oc = oc0 + o;
    size_t base = ((size_t)(b * 64 + oc) * 96 + h) * 96 + w0;
    dst[base + 0] = acc[o][0];
    dst[base + 1] = acc[o][1];
    dst[base + 2] = acc[o][2];
  }
}

// 1536 blocks (6/CU), uniform-ish work {9,8,8,10} units; type interleaved via bid&3
__global__ __launch_bounds__(256, 6) void deform_all(const float* __restrict__ x,
                                                     const float* __restrict__ offAll,
                                                     const float* __restrict__ w1T,
                                                     const float* __restrict__ w3T,
                                                     const float* __restrict__ w5T,
                                                     float* __restrict__ x1,
                                                     float* __restrict__ x2,
                                                     float* __restrict__ x3a,
                                                     float* __restrict__ x3b,
                                                     float* __restrict__ x3c) {
  __shared__ __align__(16) float xoffn[32 * 96];
  __shared__ __align__(16) float wn[32 * 64];
  __shared__ int   sp_i[4 * 96];
  __shared__ float sp_g[4 * 96];
  int bid = blockIdx.x;
  int typ = bid & 3, idx = bid >> 2;
  int h = idx % 96, b = idx / 96;
  int tid = threadIdx.x;
  if (typ == 0)      deform_body<5>(x, offAll, w5T, x3a, 0, 9,  xoffn, wn, sp_i, sp_g, h, b, tid);
  else if (typ == 1) deform_body<5>(x, offAll, w5T, x3b, 9, 17, xoffn, wn, sp_i, sp_g, h, b, tid);
  else if (typ == 2) deform_body<5>(x, offAll, w5T, x3c, 17, 25, xoffn, wn, sp_i, sp_g, h, b, tid);
  else {
    deform_body<3>(x, offAll, w3T, x2, 0, 9, xoffn, wn, sp_i, sp_g, h, b, tid);
    deform_body<1>(x, offAll, w1T, x1, 0, 1, xoffn, wn, sp_i, sp_g, h, b, tid);
  }
}

// ---------------- msf materialization: msf = lr(x1+b1)+lr(x2+b3)+lr(x3a+x3b+x3c+b5) ----------------
__global__ __launch_bounds__(256) void msf_build(const float* __restrict__ x1,
                                                 const float* __restrict__ x2,
                                                 const float* __restrict__ x3a,
                                                 const float* __restrict__ x3b,
                                                 const float* __restrict__ x3c,
                                                 const float* __restrict__ b1,
                                                 const float* __restrict__ b3,
                                                 const float* __restrict__ b5,
                                                 float* __restrict__ msf) {
  int i = blockIdx.x * 256 + threadIdx.x;           // 589824 float4s
  int c = (i / 2304) & 63;                          // HW/4 = 2304
  float bb1 = b1[c], bb3 = b3[c], bb5 = b5[c];
  float4 v1 = reinterpret_cast<const float4*>(x1)[i];
  float4 v2 = reinterpret_cast<const float4*>(x2)[i];
  float4 va = reinterpret_cast<const float4*>(x3a)[i];
  float4 vb = reinterpret_cast<const float4*>(x3b)[i];
  float4 vc = reinterpret_cast<const float4*>(x3c)[i];
  float4 m;
  {
    float a1 = v1.x + bb1; a1 = a1 >= 0.f ? a1 : 0.1f * a1;
    float a2 = v2.x + bb3; a2 = a2 >= 0.f ? a2 : 0.1f * a2;
    float a3 = va.x + vb.x + vc.x + bb5; a3 = a3 >= 0.f ? a3 : 0.1f * a3;
    m.x = a1 + a2 + a3;
  }
  {
    float a1 = v1.y + bb1; a1 = a1 >= 0.f ? a1 : 0.1f * a1;
    float a2 = v2.y + bb3; a2 = a2 >= 0.f ? a2 : 0.1f * a2;
    float a3 = va.y + vb.y + vc.y + bb5; a3 = a3 >= 0.f ? a3 : 0.1f * a3;
    m.y = a1 + a2 + a3;
  }
  {
    float a1 = v1.z + bb1; a1 = a1 >= 0.f ? a1 : 0.1f * a1;
    float a2 = v2.z + bb3; a2 = a2 >= 0.f ? a2 : 0.1f * a2;
    float a3 = va.z + vb.z + vc.z + bb5; a3 = a3 >= 0.f ? a3 : 0.1f * a3;
    m.z = a1 + a2 + a3;
  }
  {
    float a1 = v1.w + bb1; a1 = a1 >= 0.f ? a1 : 0.1f * a1;
    float a2 = v2.w + bb3; a2 = a2 >= 0.f ? a2 : 0.1f * a2;
    float a3 = va.w + vb.w + vc.w + bb5; a3 = a3 >= 0.f ? a3 : 0.1f * a3;
    m.w = a1 + a2 + a3;
  }
  reinterpret_cast<float4*>(msf)[i] = m;
}

// ---------------- attention (combined 5x5) + final; reads materialized msf ----------------
__global__ __launch_bounds__(128, 2) void att_final(const float* __restrict__ msf,
                                                    const float* __restrict__ weff,
                                                    const float* __restrict__ beff,
                                                    float* __restrict__ out) {
  __shared__ __align__(16) float xs[4 * 5 * 100];
  __shared__ __align__(16) float wsh[4 * 25 * 32];
  const int h = blockIdx.x, b = blockIdx.y, zoc = blockIdx.z * 32;
  const int tid = threadIdx.x;
  const int ocg = tid >> 5, colg = tid & 31;
  const int oc0 = ocg * 8, w0 = colg * 3;
  float acc[8][3] = {};

  for (int cc = 0; cc < 16; ++cc) {
    __syncthreads();
    for (int idx = tid; idx < 2000; idx += 128) {
      int ic = idx / 500, r = (idx / 100) % 5, j = idx % 100;
      int hr = h - 2 + r, wc = j - 2;
      float v = 0.f;
      if (hr >= 0 && hr < 96 && wc >= 0 && wc < 96)
        v = msf[((size_t)(b * 64 + cc * 4 + ic) * 96 + hr) * 96 + wc];
      xs[idx] = v;
    }
    for (int i = tid; i < 800; i += 128) {  // wsh[ic][tap][32]
      int ict = i >> 3, o4 = i & 7;
      int ic = ict / 25, tap = ict % 25;
      reinterpret_cast<float4*>(wsh)[i] =
          *reinterpret_cast<const float4*>(weff + ((size_t)(cc * 4 + ic) * 25 + tap) * 64 + zoc + o4 * 4);
    }
    __syncthreads();
#pragma unroll
    for (int ic = 0; ic < 4; ++ic) {
#pragma unroll
      for (int kh = 0; kh < 5; ++kh) {
        float xv[7];
#pragma unroll
        for (int t = 0; t < 7; ++t) xv[t] = xs[ic * 500 + kh * 100 + w0 + t];
#pragma unroll
        for (int kw = 0; kw < 5; ++kw) {
          const float4* wp = reinterpret_cast<const float4*>(&wsh[(ic * 25 + kh * 5 + kw) * 32 + oc0]);
          float4 wa = wp[0], wb = wp[1];
          float wv[8] = {wa.x, wa.y, wa.z, wa.w, wb.x, wb.y, wb.z, wb.w};
#pragma unroll
          for (int o = 0; o < 8; ++o) {
            acc[o][0] += wv[o] * xv[kw + 0];
            acc[o][1] += wv[o] * xv[kw + 1];
            acc[o][2] += wv[o] * xv[kw + 2];
          }
        }
      }
    }
  }
#pragma unroll
  for (int o = 0; o < 8; ++o) {
    int oc = zoc + oc0 + o;
    float bz = beff[oc];
#pragma unroll
    for (int p = 0; p < 3; ++p) {
      float z = acc[o][p] + bz;
      float att = 1.f / (1.f + __expf(-z));
      size_t oi = ((size_t)(b * 64 + oc) * 96 + h) * 96 + w0 + p;
      float m = msf[oi];
      out[oi] = m + m * att;
    }
  }
}

// ---------------- launch ----------------
extern "C" void kernel_launch(void* const* d_in, const int* in_sizes, int n_in,
                              void* d_out, int out_size, void* d_ws, size_t ws_size,
                              hipStream_t stream) {
  const float* x   = (const float*)d_in[0];
  const float* wo1 = (const float*)d_in[1];
  const float* bo1 = (const float*)d_in[2];
  const float* w1  = (const float*)d_in[3];
  const float* b1  = (const float*)d_in[4];
  const float* wa1 = (const float*)d_in[5];
  const float* ba1 = (const float*)d_in[6];
  const float* wo3 = (const float*)d_in[7];
  const float* bo3 = (const float*)d_in[8];
  const float* w3  = (const float*)d_in[9];
  const float* b3  = (const float*)d_in[10];
  const float* wa3 = (const float*)d_in[11];
  const float* ba3 = (const float*)d_in[12];
  const float* wo5 = (const float*)d_in[13];
  const float* bo5 = (const float*)d_in[14];
  const float* w5  = (const float*)d_in[15];
  const float* b5  = (const float*)d_in[16];
  const float* wa5 = (const float*)d_in[17];
  const float* ba5 = (const float*)d_in[18];

  float* ws     = (float*)d_ws;
  float* offAll = ws + OFF_OFFALL;
  float* msf    = ws + OFF_MSF;
  float* x1     = ws + OFF_X1;
  float* x2     = ws + OFF_X2;
  float* x3a    = ws + OFF_X3A;
  float* x3b    = ws + OFF_X3B;
  float* x3c    = ws + OFF_X3C;
  float* woT    = ws + OFF_WOT;
  float* boAll  = ws + OFF_BOALL;
  float* w1T    = ws + OFF_W1T;
  float* w3T    = ws + OFF_W3T;
  float* w5T    = ws + OFF_W5T;
  float* weff   = ws + OFF_WEFF;
  float* beff   = ws + OFF_BEFF;

  float* out = (float*)d_out;

  hipLaunchKernelGGL(prep_all, dim3(1122), dim3(256), 0, stream,
                     wo1, bo1, wo3, bo3, wo5, bo5, w1, w3, w5,
                     wa1, ba1, wa3, ba3, wa5, ba5,
                     woT, boAll, w1T, w3T, w5T, weff, beff);
  hipLaunchKernelGGL(conv_off, dim3(96, 4), dim3(256), 0, stream, x, woT, boAll, offAll);
  hipLaunchKernelGGL(deform_all, dim3(1536), dim3(256), 0, stream,
                     x, offAll, w1T, w3T, w5T, x1, x2, x3a, x3b, x3c);
  hipLaunchKernelGGL(msf_build, dim3(2304), dim3(256), 0, stream,
                     x1, x2, x3a, x3b, x3c, b1, b3, b5, msf);
  hipLaunchKernelGGL(att_final, dim3(96, 4, 2), dim3(128), 0, stream,
                     msf, weff, beff, out);
}

// Round 5
// 705.548 us; speedup vs baseline: 1.1530x; 1.0632x over previous
//
#include <hip/hip_runtime.h>
#include <math.h>

constexpr int B = 4, C = 64, H = 96, W = 96, HW = H * W;
constexpr int HWP = 100 * 100;  // padded plane (2-halo)

typedef __attribute__((ext_vector_type(8))) short bf16x8;
typedef __attribute__((ext_vector_type(4))) float f32x4;
typedef __attribute__((ext_vector_type(4))) unsigned int uint4v;

// ---- workspace layout (float offsets), total ~12.6M floats = 50.3 MB ----
constexpr size_t OFF_OFFALL = 0;                               // B*72*HW
constexpr size_t OFF_X1     = OFF_OFFALL + (size_t)B*72*HW;    // raw deform1 sum
constexpr size_t OFF_X2     = OFF_X1  + (size_t)B*64*HW;       // raw deform3 sum
constexpr size_t OFF_X3     = OFF_X2  + (size_t)B*64*HW;       // raw deform5 sum (atomic)
constexpr size_t OFF_XPAD   = OFF_X3  + (size_t)B*64*HW;       // B*64*100*100 padded x
constexpr size_t OFF_MSF    = OFF_XPAD;                        // alias: xpad dead after deform
constexpr size_t OFF_WOT    = OFF_XPAD + (size_t)B*64*HWP;     // 64*9*72 [ic][tap][oc]
constexpr size_t OFF_BOALL  = OFF_WOT + (size_t)64*9*72;       // 72 (pad 128)
constexpr size_t OFF_WPKH   = OFF_BOALL + 128;                 // 143360 ushort = 71680 f
constexpr size_t OFF_WPKL   = OFF_WPKH + 71680;                // 143360 ushort
constexpr size_t OFF_WEFF   = OFF_WPKL + 71680;                // 64*25*64
constexpr size_t OFF_BEFF   = OFF_WEFF + (size_t)64*25*64;     // 64

// ---------------- prep: weight transforms + bf16 hi/lo fragment packing ----------------
__global__ void prep_all(const float* __restrict__ wo1, const float* __restrict__ bo1,
                         const float* __restrict__ wo3, const float* __restrict__ bo3,
                         const float* __restrict__ wo5, const float* __restrict__ bo5,
                         const float* __restrict__ w1, const float* __restrict__ w3,
                         const float* __restrict__ w5,
                         const float* __restrict__ wa1, const float* __restrict__ ba1,
                         const float* __restrict__ wa3, const float* __restrict__ ba3,
                         const float* __restrict__ wa5, const float* __restrict__ ba5,
                         float* __restrict__ woT, float* __restrict__ boAll,
                         unsigned short* __restrict__ wPkH, unsigned short* __restrict__ wPkL,
                         float* __restrict__ weff, float* __restrict__ beff) {
  int idx = blockIdx.x * 256 + threadIdx.x;
  if (idx < 41472) {  // woT [ic64][tap9][oc72]
    int ic = idx / (9 * 72), tap = (idx / 72) % 9, oc = idx % 72;
    float v = 0.f;
    if (oc < 2)       v = wo1[(oc * 64 + ic) * 9 + tap];
    else if (oc < 20) v = wo3[((oc - 2) * 64 + ic) * 9 + tap];
    else if (oc < 70) v = wo5[((oc - 20) * 64 + ic) * 9 + tap];
    woT[idx] = v;
  }
  if (idx < 72) boAll[idx] = idx < 2 ? bo1[idx] : idx < 20 ? bo3[idx - 2] : idx < 70 ? bo5[idx - 20] : 0.f;
  if (idx < 64) beff[idx] = ba1[idx] + ba3[idx] + ba5[idx];
  int i3 = idx - 41472;  // weff 64*25*64 [ic][tap][oc]
  if (i3 >= 0 && i3 < 102400) {
    int ic = i3 / 1600, tap = (i3 / 64) % 25, oc = i3 & 63;
    int kh = tap / 5, kw = tap % 5;
    float v = wa5[(oc * 64 + ic) * 25 + tap];
    if (kh >= 1 && kh <= 3 && kw >= 1 && kw <= 3)
      v += wa3[(oc * 64 + ic) * 9 + (kh - 1) * 3 + (kw - 1)];
    if (tap == 12) v += wa1[oc * 64 + ic];
    weff[i3] = v;
  }
  // deform weight pack: e = (((tap*2+kt)*4+nt)*64 + lane)*8 + i
  // A/B shared k-slot convention: c = kt*32 + 8*(lane>>4) + i ; oc = nt*16 + (lane&15)
  int e = idx - 143872;
  if (e >= 0 && e < 143360) {
    int i  = e & 7;
    int l  = (e >> 3) & 63;
    int nt = (e >> 9) & 3;
    int kt = (e >> 11) & 1;
    int tap = e >> 12;                       // global: 0=KS1, 1..9=KS3, 10..34=KS5
    int c  = kt * 32 + 8 * (l >> 4) + i;
    int oc = nt * 16 + (l & 15);
    float w;
    if (tap == 0)      w = w1[oc * 64 + c];
    else if (tap < 10) w = w3[(oc * 64 + c) * 9 + (tap - 1)];
    else               w = w5[(oc * 64 + c) * 25 + (tap - 10)];
    unsigned bits = __float_as_uint(w);
    unsigned hib  = bits & 0xffff0000u;
    float lo = w - __uint_as_float(hib);
    wPkH[e] = (unsigned short)(bits >> 16);
    wPkL[e] = (unsigned short)(__float_as_uint(lo) >> 16);
  }
}

// ---------------- padded input: xpad[b][c][100][100], 2-halo zeros ----------------
__global__ void pad_x(const float* __restrict__ x, float* __restrict__ xpad) {
  int i = blockIdx.x * 256 + threadIdx.x;
  if (i >= B * 64 * HWP) return;
  int u = i % HWP, bc = i / HWP;
  int r = u / 100, col = u % 100;
  float v = 0.f;
  if (r >= 2 && r < 98 && col >= 2 && col < 98)
    v = x[(size_t)bc * HW + (r - 2) * 96 + (col - 2)];
  xpad[i] = v;
}

__global__ void zero_buf(float* __restrict__ p) {
  int i = blockIdx.x * 256 + threadIdx.x;  // 2304*256 float4 = B*64*HW
  reinterpret_cast<float4*>(p)[i] = make_float4(0.f, 0.f, 0.f, 0.f);
}

// ---------------- offset conv: 3x3 pad1, 64->72 ch; z splits oc {40,32} ----------------
template <int NOC, int OCB>
__device__ __forceinline__ void conv_off_body(const float* __restrict__ x,
                                              const float* __restrict__ woT,
                                              const float* __restrict__ boAll,
                                              float* __restrict__ offAll,
                                              float* __restrict__ xs,    // [8][3][100]
                                              float* __restrict__ wsh,   // [8*9*NOC]
                                              int h, int b, int tid) {
  constexpr int OCPG = NOC / 8;
  const int ocg = tid >> 5, pixg = tid & 31;
  const int oc0 = ocg * OCPG, w0 = pixg * 3;
  float acc[OCPG][3] = {};

  for (int cc = 0; cc < 8; ++cc) {
    __syncthreads();
    for (int idx = tid; idx < 2400; idx += 256) {
      int ic = idx / 300, r = (idx / 100) % 3, j = idx % 100;
      int wc = j - 1, hr = h - 1 + r;
      float v = 0.f;
      if (wc >= 0 && wc < 96 && hr >= 0 && hr < 96)
        v = x[((size_t)(b * 64 + cc * 8 + ic) * 96 + hr) * 96 + wc];
      xs[(ic * 3 + r) * 100 + j] = v;
    }
    for (int i = tid; i < 8 * 9 * NOC; i += 256) {
      int ic = i / (9 * NOC), rem = i % (9 * NOC), tap = rem / NOC, j = rem % NOC;
      wsh[i] = woT[((size_t)(cc * 8 + ic) * 9 + tap) * 72 + OCB + j];
    }
    __syncthreads();
#pragma unroll 2
    for (int ic = 0; ic < 8; ++ic) {
#pragma unroll
      for (int kh = 0; kh < 3; ++kh) {
        float xv[5];
#pragma unroll
        for (int t = 0; t < 5; ++t) xv[t] = xs[(ic * 3 + kh) * 100 + w0 + t];
#pragma unroll
        for (int kw = 0; kw < 3; ++kw) {
          const float* wrow = &wsh[(ic * 9 + kh * 3 + kw) * NOC + oc0];
#pragma unroll
          for (int o = 0; o < OCPG; ++o) {
            float wv = wrow[o];
            acc[o][0] += wv * xv[kw + 0];
            acc[o][1] += wv * xv[kw + 1];
            acc[o][2] += wv * xv[kw + 2];
          }
        }
      }
    }
  }
#pragma unroll
  for (int o = 0; o < OCPG; ++o) {
    int oc = OCB + oc0 + o;
    float bias = boAll[oc];
#pragma unroll
    for (int p = 0; p < 3; ++p)
      offAll[((size_t)(b * 72 + oc) * 96 + h) * 96 + w0 + p] = acc[o][p] + bias;
  }
}

__global__ __launch_bounds__(256) void conv_off(const float* __restrict__ x,
                                                const float* __restrict__ woT,
                                                const float* __restrict__ boAll,
                                                float* __restrict__ offAll) {
  __shared__ __align__(16) float xs[8 * 3 * 100];
  __shared__ __align__(16) float wsh[8 * 9 * 40];
  const int h = blockIdx.x, b = blockIdx.y, tid = threadIdx.x;
  if (blockIdx.z == 0) conv_off_body<40, 0>(x, woT, boAll, offAll, xs, wsh, h, b, tid);
  else                 conv_off_body<32, 40>(x, woT, boAll, offAll, xs, wsh, h, b, tid);
}

// ---------------- deformable conv via bf16-split MFMA ----------------
// Block: 2 rows (192 px), 4 waves; wave w owns px [48w,48w+48) = 3 m-tiles of 16.
// Per wave: all 64 oc = 4 n-tiles. K = 64 c = 2 k-steps of 32.
// A-frag (lane l): m = l&15 (px), k-slot (l>>4, i) -> c = kt*32+8*(l>>4)+i, gathered
// bilinearly from xpad directly into registers, split hi/lo bf16 (3-term MFMA).
template <int KS, bool ATOMIC>
__device__ __forceinline__ void deform_mfma_body(const float* __restrict__ xpb,
                                                 const float* __restrict__ offAll,
                                                 const unsigned short* __restrict__ wPkH,
                                                 const unsigned short* __restrict__ wPkL,
                                                 float* __restrict__ dst,
                                                 int n0, int n1, int b, int h0,
                                                 int* __restrict__ spb, int* __restrict__ spd,
                                                 float* __restrict__ spg, int tid) {
  constexpr int N = KS * KS, P = (KS - 1) / 2, S = 2 - P, HP = H + 2 * P;
  constexpr int CHB = KS == 1 ? 0 : KS == 3 ? 2 : 20;   // offset channel base
  constexpr int GB  = KS == 1 ? 0 : KS == 3 ? 1 : 10;   // global tap base in pack
  const int lane = tid & 63, wv = tid >> 6;
  const int pxw = wv * 48, lg = lane >> 4, lm = lane & 15;
  f32x4 acc[3][4];
#pragma unroll
  for (int a1 = 0; a1 < 3; ++a1)
#pragma unroll
    for (int a2 = 0; a2 < 4; ++a2) acc[a1][a2] = (f32x4)0.f;

  for (int n = n0; n < n1; ++n) {
    if (tid < 192) {
      int w = tid % 96, r = tid / 96, h = h0 + r;
      float ox = offAll[((size_t)(b * 72 + CHB + n) * 96 + h) * 96 + w];
      float oy = offAll[((size_t)(b * 72 + CHB + N + n) * 96 + h) * 96 + w];
      float px = ox + (float)(h + 1 + n / KS - P);
      float py = oy + (float)(w + 1 + n % KS - P);
      float fx = floorf(px), fy = floorf(py);
      float hpm = (float)(HP - 1);
      float ltx = fminf(fmaxf(fx, 0.f), hpm);
      float rbx = fminf(fmaxf(fx + 1.f, 0.f), hpm);
      float lty = fminf(fmaxf(fy, 0.f), hpm);
      float rby = fminf(fmaxf(fy + 1.f, 0.f), hpm);
      float pxc = fminf(fmaxf(px, 0.f), hpm);
      float pyc = fminf(fmaxf(py, 0.f), hpm);
      float gx0 = 1.f + (ltx - pxc);
      float gx1 = 1.f - (rbx - pxc);
      float gy0 = 1.f + (lty - pyc);
      float gy1 = 1.f - (rby - pyc);
      int ix0 = (int)ltx, ix1 = (int)rbx, iy0 = (int)lty, iy1 = (int)rby;
      spb[tid] = (ix0 + S) * 100 + iy0 + S;
      spd[tid] = (ix1 - ix0) * 100 + ((iy1 - iy0) << 16);
      spg[0 * 192 + tid] = gx0 * gy0;  // (ix0,iy0)
      spg[1 * 192 + tid] = gx1 * gy1;  // (ix1,iy1)
      spg[2 * 192 + tid] = gx0 * gy1;  // (ix0,iy1)
      spg[3 * 192 + tid] = gx1 * gy0;  // (ix1,iy0)
    }
    __syncthreads();
#pragma unroll
    for (int kt = 0; kt < 2; ++kt) {
      const int bb = (((GB + n) * 2 + kt)) * 256 + lane;  // 16B-unit index
      uint4v bh[4], bl[4];
#pragma unroll
      for (int nt = 0; nt < 4; ++nt) {
        bh[nt] = reinterpret_cast<const uint4v*>(wPkH)[bb + nt * 64];
        bl[nt] = reinterpret_cast<const uint4v*>(wPkL)[bb + nt * 64];
      }
#pragma unroll
      for (int mt = 0; mt < 3; ++mt) {
        int px = pxw + mt * 16 + lm;
        int base = spb[px];
        int d = spd[px];
        int dx = d & 0xffff, dy = d >> 16;
        float g0 = spg[px], g1 = spg[192 + px], g2 = spg[384 + px], g3 = spg[576 + px];
        const float* xc = xpb + (kt * 32 + lg * 8) * HWP + base;
        float vv[8];
#pragma unroll
        for (int i = 0; i < 8; ++i) {
          const float* p = xc + i * HWP;
          vv[i] = g0 * p[0] + g1 * p[dx + dy] + g2 * p[dy] + g3 * p[dx];
        }
        unsigned hp[4], lp[4];
#pragma unroll
        for (int j = 0; j < 4; ++j) {
          unsigned b0 = __float_as_uint(vv[2 * j]), b1 = __float_as_uint(vv[2 * j + 1]);
          unsigned h0b = b0 & 0xffff0000u, h1b = b1 & 0xffff0000u;
          float l0 = vv[2 * j] - __uint_as_float(h0b);
          float l1 = vv[2 * j + 1] - __uint_as_float(h1b);
          hp[j] = (b0 >> 16) | h1b;
          lp[j] = (__float_as_uint(l0) >> 16) | (__float_as_uint(l1) & 0xffff0000u);
        }
        uint4v hv = {hp[0], hp[1], hp[2], hp[3]};
        uint4v lv = {lp[0], lp[1], lp[2], lp[3]};
        bf16x8 ah = __builtin_bit_cast(bf16x8, hv);
        bf16x8 al = __builtin_bit_cast(bf16x8, lv);
#pragma unroll
        for (int nt = 0; nt < 4; ++nt) {
          bf16x8 BH = __builtin_bit_cast(bf16x8, bh[nt]);
          bf16x8 BL = __builtin_bit_cast(bf16x8, bl[nt]);
          acc[mt][nt] = __builtin_amdgcn_mfma_f32_16x16x32_bf16(ah, BH, acc[mt][nt], 0, 0, 0);
          acc[mt][nt] = __builtin_amdgcn_mfma_f32_16x16x32_bf16(al, BH, acc[mt][nt], 0, 0, 0);
          acc[mt][nt] = __builtin_amdgcn_mfma_f32_16x16x32_bf16(ah, BL, acc[mt][nt], 0, 0, 0);
        }
      }
    }
    __syncthreads();
  }
  // store: D layout (verified m89): col(oc)=lane&15, row(px)=(lane>>4)*4+reg
#pragma unroll
  for (int mt = 0; mt < 3; ++mt) {
#pragma unroll
    for (int reg = 0; reg < 4; ++reg) {
      int px = pxw + mt * 16 + lg * 4 + reg;
      int rr = px >= 96 ? 1 : 0;
      int wcol = px - rr * 96;
#pragma unroll
      for (int nt = 0; nt < 4; ++nt) {
        int oc = nt * 16 + lm;
        size_t ai = ((size_t)(b * 64 + oc) * 96 + h0 + rr) * 96 + wcol;
        float val = acc[mt][nt][reg];
        if (ATOMIC) atomicAdd(&dst[ai], val);
        else        dst[ai] = val;
      }
    }
  }
}

// 768 blocks (3/CU); typ = bid&3: {KS5 n0-9, KS5 n9-17, KS5 n17-25 (atomic x3), KS3+KS1}
__global__ __launch_bounds__(256, 3) void deform_mfma(const float* __restrict__ xpad,
                                                      const float* __restrict__ offAll,
                                                      const unsigned short* __restrict__ wPkH,
                                                      const unsigned short* __restrict__ wPkL,
                                                      float* __restrict__ x1,
                                                      float* __restrict__ x2,
                                                      float* __restrict__ x3) {
  __shared__ int spb[192], spd[192];
  __shared__ float spg[4 * 192];
  int bid = blockIdx.x;
  int typ = bid & 3, idx = bid >> 2;
  int h0 = (idx % 48) * 2, b = idx / 48;
  int tid = threadIdx.x;
  const float* xpb = xpad + (size_t)b * 64 * HWP;
  if (typ == 0)
    deform_mfma_body<5, true>(xpb, offAll, wPkH, wPkL, x3, 0, 9, b, h0, spb, spd, spg, tid);
  else if (typ == 1)
    deform_mfma_body<5, true>(xpb, offAll, wPkH, wPkL, x3, 9, 17, b, h0, spb, spd, spg, tid);
  else if (typ == 2)
    deform_mfma_body<5, true>(xpb, offAll, wPkH, wPkL, x3, 17, 25, b, h0, spb, spd, spg, tid);
  else {
    deform_mfma_body<3, false>(xpb, offAll, wPkH, wPkL, x2, 0, 9, b, h0, spb, spd, spg, tid);
    deform_mfma_body<1, false>(xpb, offAll, wPkH, wPkL, x1, 0, 1, b, h0, spb, spd, spg, tid);
  }
}

// ---------------- msf = lr(x1+b1)+lr(x2+b3)+lr(x3+b5) ----------------
__global__ __launch_bounds__(256) void msf_build(const float* __restrict__ x1,
                                                 const float* __restrict__ x2,
                                                 const float* __restrict__ x3,
                                                 const float* __restrict__ b1,
                                                 const float* __restrict__ b3,
                                                 const float* __restrict__ b5,
                                                 float* __restrict__ msf) {
  int i = blockIdx.x * 256 + threadIdx.x;  // 589824 float4s
  int c = (i / 2304) & 63;
  float bb1 = b1[c], bb3 = b3[c], bb5 = b5[c];
  float4 v1 = reinterpret_cast<const float4*>(x1)[i];
  float4 v2 = reinterpret_cast<const float4*>(x2)[i];
  float4 v3 = reinterpret_cast<const float4*>(x3)[i];
  float4 m;
  float a1, a2, a3;
  a1 = v1.x + bb1; a1 = a1 >= 0.f ? a1 : 0.1f * a1;
  a2 = v2.x + bb3; a2 = a2 >= 0.f ? a2 : 0.1f * a2;
  a3 = v3.x + bb5; a3 = a3 >= 0.f ? a3 : 0.1f * a3;
  m.x = a1 + a2 + a3;
  a1 = v1.y + bb1; a1 = a1 >= 0.f ? a1 : 0.1f * a1;
  a2 = v2.y + bb3; a2 = a2 >= 0.f ? a2 : 0.1f * a2;
  a3 = v3.y + bb5; a3 = a3 >= 0.f ? a3 : 0.1f * a3;
  m.y = a1 + a2 + a3;
  a1 = v1.z + bb1; a1 = a1 >= 0.f ? a1 : 0.1f * a1;
  a2 = v2.z + bb3; a2 = a2 >= 0.f ? a2 : 0.1f * a2;
  a3 = v3.z + bb5; a3 = a3 >= 0.f ? a3 : 0.1f * a3;
  m.z = a1 + a2 + a3;
  a1 = v1.w + bb1; a1 = a1 >= 0.f ? a1 : 0.1f * a1;
  a2 = v2.w + bb3; a2 = a2 >= 0.f ? a2 : 0.1f * a2;
  a3 = v3.w + bb5; a3 = a3 >= 0.f ? a3 : 0.1f * a3;
  m.w = a1 + a2 + a3;
  reinterpret_cast<float4*>(msf)[i] = m;
}

// ---------------- attention (combined 5x5) + final; oc split 4 -> 1536 blocks ----------------
__global__ __launch_bounds__(128) void att_final(const float* __restrict__ msf,
                                                 const float* __restrict__ weff,
                                                 const float* __restrict__ beff,
                                                 float* __restrict__ out) {
  __shared__ __align__(16) float xs[4 * 5 * 100];
  __shared__ __align__(16) float wsh[4 * 25 * 16];
  const int h = blockIdx.x, b = blockIdx.y, zoc = blockIdx.z * 16;
  const int tid = threadIdx.x;
  const int ocg = tid >> 5, colg = tid & 31;
  const int oc0 = ocg * 4, w0 = colg * 3;
  float acc[4][3] = {};

  for (int cc = 0; cc < 16; ++cc) {
    __syncthreads();
    for (int idx = tid; idx < 2000; idx += 128) {
      int ic = idx / 500, r = (idx / 100) % 5, j = idx % 100;
      int hr = h - 2 + r, wc = j - 2;
      float v = 0.f;
      if (hr >= 0 && hr < 96 && wc >= 0 && wc < 96)
        v = msf[((size_t)(b * 64 + cc * 4 + ic) * 96 + hr) * 96 + wc];
      xs[idx] = v;
    }
    for (int i = tid; i < 400; i += 128) {  // wsh[ic][tap][16]
      int ict = i >> 2, q = i & 3;
      int ic = ict / 25, tap = ict % 25;
      reinterpret_cast<float4*>(wsh)[i] =
          *reinterpret_cast<const float4*>(weff + ((size_t)(cc * 4 + ic) * 25 + tap) * 64 + zoc + q * 4);
    }
    __syncthreads();
#pragma unroll
    for (int ic = 0; ic < 4; ++ic) {
#pragma unroll
      for (int kh = 0; kh < 5; ++kh) {
        float xv[7];
#pragma unroll
        for (int t = 0; t < 7; ++t) xv[t] = xs[ic * 500 + kh * 100 + w0 + t];
#pragma unroll
        for (int kw = 0; kw < 5; ++kw) {
          const float4 wv = *reinterpret_cast<const float4*>(&wsh[(ic * 25 + kh * 5 + kw) * 16 + oc0]);
          float wvv[4] = {wv.x, wv.y, wv.z, wv.w};
#pragma unroll
          for (int o = 0; o < 4; ++o) {
            acc[o][0] += wvv[o] * xv[kw + 0];
            acc[o][1] += wvv[o] * xv[kw + 1];
            acc[o][2] += wvv[o] * xv[kw + 2];
          }
        }
      }
    }
  }
#pragma unroll
  for (int o = 0; o < 4; ++o) {
    int oc = zoc + oc0 + o;
    float bz = beff[oc];
#pragma unroll
    for (int p = 0; p < 3; ++p) {
      float z = acc[o][p] + bz;
      float att = 1.f / (1.f + __expf(-z));
      size_t oi = ((size_t)(b * 64 + oc) * 96 + h) * 96 + w0 + p;
      float m = msf[oi];
      out[oi] = m + m * att;
    }
  }
}

// ---------------- launch ----------------
extern "C" void kernel_launch(void* const* d_in, const int* in_sizes, int n_in,
                              void* d_out, int out_size, void* d_ws, size_t ws_size,
                              hipStream_t stream) {
  const float* x   = (const float*)d_in[0];
  const float* wo1 = (const float*)d_in[1];
  const float* bo1 = (const float*)d_in[2];
  const float* w1  = (const float*)d_in[3];
  const float* b1  = (const float*)d_in[4];
  const float* wa1 = (const float*)d_in[5];
  const float* ba1 = (const float*)d_in[6];
  const float* wo3 = (const float*)d_in[7];
  const float* bo3 = (const float*)d_in[8];
  const float* w3  = (const float*)d_in[9];
  const float* b3  = (const float*)d_in[10];
  const float* wa3 = (const float*)d_in[11];
  const float* ba3 = (const float*)d_in[12];
  const float* wo5 = (const float*)d_in[13];
  const float* bo5 = (const float*)d_in[14];
  const float* w5  = (const float*)d_in[15];
  const float* b5  = (const float*)d_in[16];
  const float* wa5 = (const float*)d_in[17];
  const float* ba5 = (const float*)d_in[18];

  float* ws     = (float*)d_ws;
  float* offAll = ws + OFF_OFFALL;
  float* x1     = ws + OFF_X1;
  float* x2     = ws + OFF_X2;
  float* x3     = ws + OFF_X3;
  float* xpad   = ws + OFF_XPAD;
  float* msf    = ws + OFF_MSF;
  float* woT    = ws + OFF_WOT;
  float* boAll  = ws + OFF_BOALL;
  unsigned short* wPkH = (unsigned short*)(ws + OFF_WPKH);
  unsigned short* wPkL = (unsigned short*)(ws + OFF_WPKL);
  float* weff   = ws + OFF_WEFF;
  float* beff   = ws + OFF_BEFF;

  float* out = (float*)d_out;

  hipLaunchKernelGGL(prep_all, dim3(1122), dim3(256), 0, stream,
                     wo1, bo1, wo3, bo3, wo5, bo5, w1, w3, w5,
                     wa1, ba1, wa3, ba3, wa5, ba5,
                     woT, boAll, wPkH, wPkL, weff, beff);
  hipLaunchKernelGGL(pad_x, dim3(10000), dim3(256), 0, stream, x, xpad);
  hipLaunchKernelGGL(zero_buf, dim3(2304), dim3(256), 0, stream, x3);
  hipLaunchKernelGGL(conv_off, dim3(96, 4, 2), dim3(256), 0, stream, x, woT, boAll, offAll);
  hipLaunchKernelGGL(deform_mfma, dim3(768), dim3(256), 0, stream,
                     xpad, offAll, wPkH, wPkL, x1, x2, x3);
  hipLaunchKernelGGL(msf_build, dim3(2304), dim3(256), 0, stream,
                     x1, x2, x3, b1, b3, b5, msf);
  hipLaunchKernelGGL(att_final, dim3(96, 4, 4), dim3(128), 0, stream,
                     msf, weff, beff, out);
}

// Round 6
// 609.811 us; speedup vs baseline: 1.3340x; 1.1570x over previous
//
#include <hip/hip_runtime.h>
#include <math.h>

constexpr int B = 4, C = 64, H = 96, W = 96, HW = H * W;

typedef __attribute__((ext_vector_type(8))) short bf16x8;
typedef __attribute__((ext_vector_type(4))) float f32x4;
typedef __attribute__((ext_vector_type(4))) unsigned int uint4v;

// ---- workspace layout (float offsets), total 14,738,112 floats = 58.95 MB ----
constexpr size_t OFF_OFFALL = 0;                               // B*72*HW (dead after deform)
constexpr size_t OFF_MSF    = OFF_OFFALL;                      // alias onto offAll
constexpr size_t OFF_X1     = OFF_OFFALL + (size_t)B*72*HW;    // raw deform1 sum
constexpr size_t OFF_X2     = OFF_X1  + (size_t)B*64*HW;       // raw deform3 sum
constexpr size_t OFF_X3A    = OFF_X2  + (size_t)B*64*HW;       // raw deform5 n[0,9)
constexpr size_t OFF_X3B    = OFF_X3A + (size_t)B*64*HW;       // raw deform5 n[9,17)
constexpr size_t OFF_X3C    = OFF_X3B + (size_t)B*64*HW;       // raw deform5 n[17,25)
constexpr size_t OFF_WOT    = OFF_X3C + (size_t)B*64*HW;       // 64*9*72 [ic][tap][oc]
constexpr size_t OFF_BOALL  = OFF_WOT + (size_t)64*9*72;       // 72 (pad 128)
constexpr size_t OFF_WPKH   = OFF_BOALL + 128;                 // 143360 ushort = 71680 f
constexpr size_t OFF_WPKL   = OFF_WPKH + 71680;                // 143360 ushort
constexpr size_t OFF_WEFF   = OFF_WPKL + 71680;                // 64*25*64
constexpr size_t OFF_BEFF   = OFF_WEFF + (size_t)64*25*64;     // 64

// ---------------- prep: weight transforms + bf16 hi/lo fragment packing ----------------
__global__ void prep_all(const float* __restrict__ wo1, const float* __restrict__ bo1,
                         const float* __restrict__ wo3, const float* __restrict__ bo3,
                         const float* __restrict__ wo5, const float* __restrict__ bo5,
                         const float* __restrict__ w1, const float* __restrict__ w3,
                         const float* __restrict__ w5,
                         const float* __restrict__ wa1, const float* __restrict__ ba1,
                         const float* __restrict__ wa3, const float* __restrict__ ba3,
                         const float* __restrict__ wa5, const float* __restrict__ ba5,
                         float* __restrict__ woT, float* __restrict__ boAll,
                         unsigned short* __restrict__ wPkH, unsigned short* __restrict__ wPkL,
                         float* __restrict__ weff, float* __restrict__ beff) {
  int idx = blockIdx.x * 256 + threadIdx.x;
  if (idx < 41472) {  // woT [ic64][tap9][oc72]
    int ic = idx / (9 * 72), tap = (idx / 72) % 9, oc = idx % 72;
    float v = 0.f;
    if (oc < 2)       v = wo1[(oc * 64 + ic) * 9 + tap];
    else if (oc < 20) v = wo3[((oc - 2) * 64 + ic) * 9 + tap];
    else if (oc < 70) v = wo5[((oc - 20) * 64 + ic) * 9 + tap];
    woT[idx] = v;
  }
  if (idx < 72) boAll[idx] = idx < 2 ? bo1[idx] : idx < 20 ? bo3[idx - 2] : idx < 70 ? bo5[idx - 20] : 0.f;
  if (idx < 64) beff[idx] = ba1[idx] + ba3[idx] + ba5[idx];
  int i3 = idx - 41472;  // weff 64*25*64 [ic][tap][oc]
  if (i3 >= 0 && i3 < 102400) {
    int ic = i3 / 1600, tap = (i3 / 64) % 25, oc = i3 & 63;
    int kh = tap / 5, kw = tap % 5;
    float v = wa5[(oc * 64 + ic) * 25 + tap];
    if (kh >= 1 && kh <= 3 && kw >= 1 && kw <= 3)
      v += wa3[(oc * 64 + ic) * 9 + (kh - 1) * 3 + (kw - 1)];
    if (tap == 12) v += wa1[oc * 64 + ic];
    weff[i3] = v;
  }
  // deform weight pack: e = (((tap*2+kt)*4+nt)*64 + lane)*8 + i
  // A/B shared k-slot convention: c = kt*32 + 8*(lane>>4) + i ; oc = nt*16 + (lane&15)
  int e = idx - 143872;
  if (e >= 0 && e < 143360) {
    int i  = e & 7;
    int l  = (e >> 3) & 63;
    int nt = (e >> 9) & 3;
    int kt = (e >> 11) & 1;
    int tap = e >> 12;                       // global: 0=KS1, 1..9=KS3, 10..34=KS5
    int c  = kt * 32 + 8 * (l >> 4) + i;
    int oc = nt * 16 + (l & 15);
    float w;
    if (tap == 0)      w = w1[oc * 64 + c];
    else if (tap < 10) w = w3[(oc * 64 + c) * 9 + (tap - 1)];
    else               w = w5[(oc * 64 + c) * 25 + (tap - 10)];
    unsigned bits = __float_as_uint(w);
    unsigned hib  = bits & 0xffff0000u;
    float lo = w - __uint_as_float(hib);
    wPkH[e] = (unsigned short)(bits >> 16);
    wPkL[e] = (unsigned short)(__float_as_uint(lo) >> 16);
  }
}

// ---------------- offset conv: 3x3 pad1, 64->72 ch; 1-D grid 768, XCD-swizzled ----------------
template <int NOC, int OCB>
__device__ __forceinline__ void conv_off_body(const float* __restrict__ x,
                                              const float* __restrict__ woT,
                                              const float* __restrict__ boAll,
                                              float* __restrict__ offAll,
                                              float* __restrict__ xs,    // [8][3][100]
                                              float* __restrict__ wsh,   // [8*9*NOC]
                                              int h, int b, int tid) {
  constexpr int OCPG = NOC / 8;
  const int ocg = tid >> 5, pixg = tid & 31;
  const int oc0 = ocg * OCPG, w0 = pixg * 3;
  float acc[OCPG][3] = {};

  for (int cc = 0; cc < 8; ++cc) {
    __syncthreads();
    for (int idx = tid; idx < 2400; idx += 256) {
      int ic = idx / 300, r = (idx / 100) % 3, j = idx % 100;
      int wc = j - 1, hr = h - 1 + r;
      float v = 0.f;
      if (wc >= 0 && wc < 96 && hr >= 0 && hr < 96)
        v = x[((size_t)(b * 64 + cc * 8 + ic) * 96 + hr) * 96 + wc];
      xs[(ic * 3 + r) * 100 + j] = v;
    }
    for (int i = tid; i < 8 * 9 * NOC; i += 256) {
      int ic = i / (9 * NOC), rem = i % (9 * NOC), tap = rem / NOC, j = rem % NOC;
      wsh[i] = woT[((size_t)(cc * 8 + ic) * 9 + tap) * 72 + OCB + j];
    }
    __syncthreads();
#pragma unroll 2
    for (int ic = 0; ic < 8; ++ic) {
#pragma unroll
      for (int kh = 0; kh < 3; ++kh) {
        float xv[5];
#pragma unroll
        for (int t = 0; t < 5; ++t) xv[t] = xs[(ic * 3 + kh) * 100 + w0 + t];
#pragma unroll
        for (int kw = 0; kw < 3; ++kw) {
          const float* wrow = &wsh[(ic * 9 + kh * 3 + kw) * NOC + oc0];
#pragma unroll
          for (int o = 0; o < OCPG; ++o) {
            float wv = wrow[o];
            acc[o][0] += wv * xv[kw + 0];
            acc[o][1] += wv * xv[kw + 1];
            acc[o][2] += wv * xv[kw + 2];
          }
        }
      }
    }
  }
#pragma unroll
  for (int o = 0; o < OCPG; ++o) {
    int oc = OCB + oc0 + o;
    float bias = boAll[oc];
#pragma unroll
    for (int p = 0; p < 3; ++p)
      offAll[((size_t)(b * 72 + oc) * 96 + h) * 96 + w0 + p] = acc[o][p] + bias;
  }
}

__global__ __launch_bounds__(256) void conv_off(const float* __restrict__ x,
                                                const float* __restrict__ woT,
                                                const float* __restrict__ boAll,
                                                float* __restrict__ offAll) {
  __shared__ __align__(16) float xs[8 * 3 * 100];
  __shared__ __align__(16) float wsh[8 * 9 * 40];
  const int bid = blockIdx.x, tid = threadIdx.x;
  const int r = bid & 7, q = bid >> 3;
  const int b = r >> 1, half = r & 1;
  const int z = q & 1, h = half * 48 + (q >> 1);
  if (z == 0) conv_off_body<40, 0>(x, woT, boAll, offAll, xs, wsh, h, b, tid);
  else        conv_off_body<32, 40>(x, woT, boAll, offAll, xs, wsh, h, b, tid);
}

// ---------------- deformable conv via bf16-split MFMA ----------------
// Block: 2 rows (192 px), 4 waves; wave w owns px [48w,48w+48) = 3 m-tiles of 16.
// OOB handled by zeroing bilinear g-weights (no padded copy, no bounds checks in gather).
template <int KS>
__device__ __forceinline__ void deform_mfma_body(const float* __restrict__ xb,
                                                 const float* __restrict__ offAll,
                                                 const unsigned short* __restrict__ wPkH,
                                                 const unsigned short* __restrict__ wPkL,
                                                 float* __restrict__ dst,
                                                 int n0, int n1, int b, int h0,
                                                 int* __restrict__ spb, int* __restrict__ spd,
                                                 float* __restrict__ spg, int tid) {
  constexpr int N = KS * KS, P = (KS - 1) / 2, HP = H + 2 * P;
  constexpr int CHB = KS == 1 ? 0 : KS == 3 ? 2 : 20;   // offset channel base
  constexpr int GB  = KS == 1 ? 0 : KS == 3 ? 1 : 10;   // global tap base in pack
  const int lane = tid & 63, wv = tid >> 6;
  const int pxw = wv * 48, lg = lane >> 4, lm = lane & 15;
  f32x4 acc[3][4];
#pragma unroll
  for (int a1 = 0; a1 < 3; ++a1)
#pragma unroll
    for (int a2 = 0; a2 < 4; ++a2) acc[a1][a2] = (f32x4)0.f;

  for (int n = n0; n < n1; ++n) {
    const int buf = n & 1;
    int* sb = spb + buf * 192;
    int* sd = spd + buf * 192;
    float* sg = spg + buf * 768;
    if (tid < 192) {
      int w = tid % 96, rr = tid / 96, h = h0 + rr;
      float ox = offAll[((size_t)(b * 72 + CHB + n) * 96 + h) * 96 + w];
      float oy = offAll[((size_t)(b * 72 + CHB + N + n) * 96 + h) * 96 + w];
      float pxf = ox + (float)(h + 1 + n / KS - P);
      float pyf = oy + (float)(w + 1 + n % KS - P);
      float fx = floorf(pxf), fy = floorf(pyf);
      float hpm = (float)(HP - 1);
      float ltx = fminf(fmaxf(fx, 0.f), hpm);
      float rbx = fminf(fmaxf(fx + 1.f, 0.f), hpm);
      float lty = fminf(fmaxf(fy, 0.f), hpm);
      float rby = fminf(fmaxf(fy + 1.f, 0.f), hpm);
      float pxc = fminf(fmaxf(pxf, 0.f), hpm);
      float pyc = fminf(fmaxf(pyf, 0.f), hpm);
      float gx0 = 1.f + (ltx - pxc);
      float gx1 = 1.f - (rbx - pxc);
      float gy0 = 1.f + (lty - pyc);
      float gy1 = 1.f - (rby - pyc);
      int rx0 = (int)ltx - P, rx1 = (int)rbx - P;
      int ry0 = (int)lty - P, ry1 = (int)rby - P;
      float vx0 = (rx0 >= 0 && rx0 < 96) ? 1.f : 0.f;
      float vx1 = (rx1 >= 0 && rx1 < 96) ? 1.f : 0.f;
      float vy0 = (ry0 >= 0 && ry0 < 96) ? 1.f : 0.f;
      float vy1 = (ry1 >= 0 && ry1 < 96) ? 1.f : 0.f;
      int cx0 = min(max(rx0, 0), 95), cx1 = min(max(rx1, 0), 95);
      int cy0 = min(max(ry0, 0), 95), cy1 = min(max(ry1, 0), 95);
      sb[tid] = cx0 * 96 + cy0;
      sd[tid] = (cx1 - cx0) * 96 | ((cy1 - cy0) << 16);
      sg[0 * 192 + tid] = gx0 * gy0 * vx0 * vy0;  // (x0,y0)
      sg[1 * 192 + tid] = gx1 * gy1 * vx1 * vy1;  // (x1,y1)
      sg[2 * 192 + tid] = gx0 * gy1 * vx0 * vy1;  // (x0,y1)
      sg[3 * 192 + tid] = gx1 * gy0 * vx1 * vy0;  // (x1,y0)
    }
    __syncthreads();
#pragma unroll
    for (int kt = 0; kt < 2; ++kt) {
      const int bb = (((GB + n) * 2 + kt)) * 256 + lane;  // 16B-unit index
      uint4v bh[4], bl[4];
#pragma unroll
      for (int nt = 0; nt < 4; ++nt) {
        bh[nt] = reinterpret_cast<const uint4v*>(wPkH)[bb + nt * 64];
        bl[nt] = reinterpret_cast<const uint4v*>(wPkL)[bb + nt * 64];
      }
#pragma unroll
      for (int mt = 0; mt < 3; ++mt) {
        int px = pxw + mt * 16 + lm;
        int base = sb[px];
        int d = sd[px];
        int dx = d & 0xffff, dy = d >> 16;
        float g0 = sg[px], g1 = sg[192 + px], g2 = sg[384 + px], g3 = sg[576 + px];
        const float* xc = xb + (size_t)(kt * 32 + lg * 8) * HW + base;
        float vv[8];
#pragma unroll
        for (int i = 0; i < 8; ++i) {
          const float* p = xc + (size_t)i * HW;
          vv[i] = g0 * p[0] + g1 * p[dx + dy] + g2 * p[dy] + g3 * p[dx];
        }
        unsigned hp[4], lp[4];
#pragma unroll
        for (int j = 0; j < 4; ++j) {
          unsigned b0 = __float_as_uint(vv[2 * j]), b1 = __float_as_uint(vv[2 * j + 1]);
          unsigned h0b = b0 & 0xffff0000u, h1b = b1 & 0xffff0000u;
          float l0 = vv[2 * j] - __uint_as_float(h0b);
          float l1 = vv[2 * j + 1] - __uint_as_float(h1b);
          hp[j] = (b0 >> 16) | h1b;
          lp[j] = (__float_as_uint(l0) >> 16) | (__float_as_uint(l1) & 0xffff0000u);
        }
        uint4v hv = {hp[0], hp[1], hp[2], hp[3]};
        uint4v lv = {lp[0], lp[1], lp[2], lp[3]};
        bf16x8 ah = __builtin_bit_cast(bf16x8, hv);
        bf16x8 al = __builtin_bit_cast(bf16x8, lv);
#pragma unroll
        for (int nt = 0; nt < 4; ++nt) {
          bf16x8 BH = __builtin_bit_cast(bf16x8, bh[nt]);
          bf16x8 BL = __builtin_bit_cast(bf16x8, bl[nt]);
          acc[mt][nt] = __builtin_amdgcn_mfma_f32_16x16x32_bf16(ah, BH, acc[mt][nt], 0, 0, 0);
          acc[mt][nt] = __builtin_amdgcn_mfma_f32_16x16x32_bf16(al, BH, acc[mt][nt], 0, 0, 0);
          acc[mt][nt] = __builtin_amdgcn_mfma_f32_16x16x32_bf16(ah, BL, acc[mt][nt], 0, 0, 0);
        }
      }
    }
    // no trailing barrier: next iter writes the other sp buffer
  }
  // store: D layout (verified m89): col(oc)=lane&15, row(px)=(lane>>4)*4+reg
#pragma unroll
  for (int mt = 0; mt < 3; ++mt) {
#pragma unroll
    for (int reg = 0; reg < 4; ++reg) {
      int px = pxw + mt * 16 + lg * 4 + reg;
      int rr = px >= 96 ? 1 : 0;
      int wcol = px - rr * 96;
#pragma unroll
      for (int nt = 0; nt < 4; ++nt) {
        int oc = nt * 16 + lm;
        dst[((size_t)(b * 64 + oc) * 96 + h0 + rr) * 96 + wcol] = acc[mt][nt][reg];
      }
    }
  }
}

// 768 blocks, XCD-swizzled: bid%8 -> (batch, strip-half); q -> (type, strip)
__global__ __launch_bounds__(256, 3) void deform_mfma(const float* __restrict__ x,
                                                      const float* __restrict__ offAll,
                                                      const unsigned short* __restrict__ wPkH,
                                                      const unsigned short* __restrict__ wPkL,
                                                      float* __restrict__ x1,
                                                      float* __restrict__ x2,
                                                      float* __restrict__ x3a,
                                                      float* __restrict__ x3b,
                                                      float* __restrict__ x3c) {
  __shared__ int spb[2 * 192], spd[2 * 192];
  __shared__ float spg[2 * 768];
  const int bid = blockIdx.x, tid = threadIdx.x;
  const int r = bid & 7, q = bid >> 3;
  const int b = r >> 1, half = r & 1;
  const int typ = q & 3, strip = half * 24 + (q >> 2);
  const int h0 = strip * 2;
  const float* xb = x + (size_t)b * 64 * HW;
  if (typ == 0)
    deform_mfma_body<5>(xb, offAll, wPkH, wPkL, x3a, 0, 9, b, h0, spb, spd, spg, tid);
  else if (typ == 1)
    deform_mfma_body<5>(xb, offAll, wPkH, wPkL, x3b, 9, 17, b, h0, spb, spd, spg, tid);
  else if (typ == 2)
    deform_mfma_body<5>(xb, offAll, wPkH, wPkL, x3c, 17, 25, b, h0, spb, spd, spg, tid);
  else {
    deform_mfma_body<3>(xb, offAll, wPkH, wPkL, x2, 0, 9, b, h0, spb, spd, spg, tid);
    __syncthreads();  // protect sp reuse between the two bodies
    deform_mfma_body<1>(xb, offAll, wPkH, wPkL, x1, 0, 1, b, h0, spb, spd, spg, tid);
  }
}

// ---------------- msf = lr(x1+b1)+lr(x2+b3)+lr(x3a+x3b+x3c+b5) ----------------
__global__ __launch_bounds__(256) void msf_build(const float* __restrict__ x1,
                                                 const float* __restrict__ x2,
                                                 const float* __restrict__ x3a,
                                                 const float* __restrict__ x3b,
                                                 const float* __restrict__ x3c,
                                                 const float* __restrict__ b1,
                                                 const float* __restrict__ b3,
                                                 const float* __restrict__ b5,
                                                 float* __restrict__ msf) {
  int i = blockIdx.x * 256 + threadIdx.x;           // 589824 float4s
  int c = (i / 2304) & 63;                          // HW/4 = 2304
  float bb1 = b1[c], bb3 = b3[c], bb5 = b5[c];
  float4 v1 = reinterpret_cast<const float4*>(x1)[i];
  float4 v2 = reinterpret_cast<const float4*>(x2)[i];
  float4 va = reinterpret_cast<const float4*>(x3a)[i];
  float4 vb = reinterpret_cast<const float4*>(x3b)[i];
  float4 vc = reinterpret_cast<const float4*>(x3c)[i];
  float4 m;
  float a1, a2, a3;
  a1 = v1.x + bb1; a1 = a1 >= 0.f ? a1 : 0.1f * a1;
  a2 = v2.x + bb3; a2 = a2 >= 0.f ? a2 : 0.1f * a2;
  a3 = va.x + vb.x + vc.x + bb5; a3 = a3 >= 0.f ? a3 : 0.1f * a3;
  m.x = a1 + a2 + a3;
  a1 = v1.y + bb1; a1 = a1 >= 0.f ? a1 : 0.1f * a1;
  a2 = v2.y + bb3; a2 = a2 >= 0.f ? a2 : 0.1f * a2;
  a3 = va.y + vb.y + vc.y + bb5; a3 = a3 >= 0.f ? a3 : 0.1f * a3;
  m.y = a1 + a2 + a3;
  a1 = v1.z + bb1; a1 = a1 >= 0.f ? a1 : 0.1f * a1;
  a2 = v2.z + bb3; a2 = a2 >= 0.f ? a2 : 0.1f * a2;
  a3 = va.z + vb.z + vc.z + bb5; a3 = a3 >= 0.f ? a3 : 0.1f * a3;
  m.z = a1 + a2 + a3;
  a1 = v1.w + bb1; a1 = a1 >= 0.f ? a1 : 0.1f * a1;
  a2 = v2.w + bb3; a2 = a2 >= 0.f ? a2 : 0.1f * a2;
  a3 = va.w + vb.w + vc.w + bb5; a3 = a3 >= 0.f ? a3 : 0.1f * a3;
  m.w = a1 + a2 + a3;
  reinterpret_cast<float4*>(msf)[i] = m;
}

// ---------------- attention (combined 5x5) + final; 768 blocks of 256thr, swizzled ----------------
__global__ __launch_bounds__(256) void att_final(const float* __restrict__ msf,
                                                 const float* __restrict__ weff,
                                                 const float* __restrict__ beff,
                                                 float* __restrict__ out) {
  __shared__ __align__(16) float xs[4 * 5 * 100];
  __shared__ __align__(16) float wsh[4 * 25 * 32];
  const int bid = blockIdx.x, tid = threadIdx.x;
  const int r = bid & 7, q = bid >> 3;
  const int b = r >> 1, half = r & 1;
  const int zhalf = q & 1, h = half * 48 + (q >> 1);
  const int zoc = zhalf * 32;
  const int ocg = tid >> 5, colg = tid & 31;
  const int oc0 = ocg * 4, w0 = colg * 3;
  float acc[4][3] = {};

  for (int cc = 0; cc < 16; ++cc) {
    __syncthreads();
    for (int idx = tid; idx < 2000; idx += 256) {
      int ic = idx / 500, rr = (idx / 100) % 5, j = idx % 100;
      int hr = h - 2 + rr, wc = j - 2;
      float v = 0.f;
      if (hr >= 0 && hr < 96 && wc >= 0 && wc < 96)
        v = msf[((size_t)(b * 64 + cc * 4 + ic) * 96 + hr) * 96 + wc];
      xs[idx] = v;
    }
    for (int i = tid; i < 800; i += 256) {  // wsh[ic][tap][32]
      int ict = i >> 3, qq = i & 7;
      int ic = ict / 25, tap = ict % 25;
      reinterpret_cast<float4*>(wsh)[i] =
          *reinterpret_cast<const float4*>(weff + ((size_t)(cc * 4 + ic) * 25 + tap) * 64 + zoc + qq * 4);
    }
    __syncthreads();
#pragma unroll
    for (int ic = 0; ic < 4; ++ic) {
#pragma unroll
      for (int kh = 0; kh < 5; ++kh) {
        float xv[7];
#pragma unroll
        for (int t = 0; t < 7; ++t) xv[t] = xs[ic * 500 + kh * 100 + w0 + t];
#pragma unroll
        for (int kw = 0; kw < 5; ++kw) {
          const float4 wv = *reinterpret_cast<const float4*>(&wsh[(ic * 25 + kh * 5 + kw) * 32 + oc0]);
          float wvv[4] = {wv.x, wv.y, wv.z, wv.w};
#pragma unroll
          for (int o = 0; o < 4; ++o) {
            acc[o][0] += wvv[o] * xv[kw + 0];
            acc[o][1] += wvv[o] * xv[kw + 1];
            acc[o][2] += wvv[o] * xv[kw + 2];
          }
        }
      }
    }
  }
#pragma unroll
  for (int o = 0; o < 4; ++o) {
    int oc = zoc + oc0 + o;
    float bz = beff[oc];
#pragma unroll
    for (int p = 0; p < 3; ++p) {
      float z = acc[o][p] + bz;
      float att = 1.f / (1.f + __expf(-z));
      size_t oi = ((size_t)(b * 64 + oc) * 96 + h) * 96 + w0 + p;
      float m = msf[oi];
      out[oi] = m + m * att;
    }
  }
}

// ---------------- launch ----------------
extern "C" void kernel_launch(void* const* d_in, const int* in_sizes, int n_in,
                              void* d_out, int out_size, void* d_ws, size_t ws_size,
                              hipStream_t stream) {
  const float* x   = (const float*)d_in[0];
  const float* wo1 = (const float*)d_in[1];
  const float* bo1 = (const float*)d_in[2];
  const float* w1  = (const float*)d_in[3];
  const float* b1  = (const float*)d_in[4];
  const float* wa1 = (const float*)d_in[5];
  const float* ba1 = (const float*)d_in[6];
  const float* wo3 = (const float*)d_in[7];
  const float* bo3 = (const float*)d_in[8];
  const float* w3  = (const float*)d_in[9];
  const float* b3  = (const float*)d_in[10];
  const float* wa3 = (const float*)d_in[11];
  const float* ba3 = (const float*)d_in[12];
  const float* wo5 = (const float*)d_in[13];
  const float* bo5 = (const float*)d_in[14];
  const float* w5  = (const float*)d_in[15];
  const float* b5  = (const float*)d_in[16];
  const float* wa5 = (const float*)d_in[17];
  const float* ba5 = (const float*)d_in[18];

  float* ws     = (float*)d_ws;
  float* offAll = ws + OFF_OFFALL;
  float* msf    = ws + OFF_MSF;
  float* x1     = ws + OFF_X1;
  float* x2     = ws + OFF_X2;
  float* x3a    = ws + OFF_X3A;
  float* x3b    = ws + OFF_X3B;
  float* x3c    = ws + OFF_X3C;
  float* woT    = ws + OFF_WOT;
  float* boAll  = ws + OFF_BOALL;
  unsigned short* wPkH = (unsigned short*)(ws + OFF_WPKH);
  unsigned short* wPkL = (unsigned short*)(ws + OFF_WPKL);
  float* weff   = ws + OFF_WEFF;
  float* beff   = ws + OFF_BEFF;

  float* out = (float*)d_out;

  hipLaunchKernelGGL(prep_all, dim3(1122), dim3(256), 0, stream,
                     wo1, bo1, wo3, bo3, wo5, bo5, w1, w3, w5,
                     wa1, ba1, wa3, ba3, wa5, ba5,
                     woT, boAll, wPkH, wPkL, weff, beff);
  hipLaunchKernelGGL(conv_off, dim3(768), dim3(256), 0, stream, x, woT, boAll, offAll);
  hipLaunchKernelGGL(deform_mfma, dim3(768), dim3(256), 0, stream,
                     x, offAll, wPkH, wPkL, x1, x2, x3a, x3b, x3c);
  hipLaunchKernelGGL(msf_build, dim3(2304), dim3(256), 0, stream,
                     x1, x2, x3a, x3b, x3c, b1, b3, b5, msf);
  hipLaunchKernelGGL(att_final, dim3(768), dim3(256), 0, stream,
                     msf, weff, beff, out);
}